// Round 8
// baseline (485.628 us; speedup 1.0000x reference)
//
#include <hip/hip_runtime.h>
#include <hip/hip_bf16.h>

// LearnableVQ forward on MI355X — v5: high-residency variant.
// B=8 H=8 L=4096 DK=64 S=512. Inputs f32; output f32, concatenated:
//   vecs_hat[B,H,L,DK] | z[B,H,L] | l_commit | l_codebook | errs2[B,H,L]
// v5 changes vs v4: 64-code chunks (LDS 19.4 KiB -> 6-8 blocks/CU),
// packed top-2 indices (1 u32), 2-pass low-register refine, lb(256,6).

#define Bc 8
#define Hc 8
#define Lc 4096
#define DKc 64
#define Sc 512

typedef __attribute__((ext_vector_type(8))) short bf16x8;
typedef __attribute__((ext_vector_type(8))) unsigned short u16x8;
typedef __attribute__((ext_vector_type(4))) float f32x4;

// ---------------- ws layout (bytes) ----------------
#define WS_C_OFF    0u          // H*S*DK f32           = 1,048,576
#define WS_C2_OFF   1048576u    // H*S f32              =    16,384
#define WS_CBH_OFF  1064960u    // H*S*DK bf16 hi (swz) =   524,288
#define WS_CBL_OFF  1589248u    // H*S*DK bf16 lo (swz) =   524,288
#define WS_PART_OFF 2113536u    // 8192 f32             =    32,768
#define NPART       8192

__device__ __forceinline__ unsigned short f32_to_bf16_rne(float x) {
    unsigned u = __float_as_uint(x);
    unsigned r = (u + 0x7FFFu + ((u >> 16) & 1u)) >> 16;
    return (unsigned short)r;
}
__device__ __forceinline__ float bf16_hi_f32(unsigned short h) {
    return __uint_as_float(((unsigned)h) << 16);
}

// ---------------- prep: normalize codebook; c2; pre-split pre-swizzled bf16 ----------------
__global__ __launch_bounds__(256) void prep_kernel(
        const float* __restrict__ c_sum,
        const float* __restrict__ c_count,
        float* __restrict__ c,
        float* __restrict__ c2,
        unsigned short* __restrict__ cbh,
        unsigned short* __restrict__ cbl) {
    int row  = (blockIdx.x * blockDim.x + threadIdx.x) >> 6;   // h*512 + s
    int lane = threadIdx.x & 63;
    float cnt = c_count[row];
    float inv = 1.0f / fmaxf(cnt, 0.01f);
    float val = c_sum[row * DKc + lane] * inv;
    c[row * DKc + lane] = val;
    unsigned short hi = f32_to_bf16_rne(val);
    unsigned short lo = f32_to_bf16_rne(val - bf16_hi_f32(hi));
    int s = row & (Sc - 1);
    size_t hbase = (size_t)(row >> 9) * (Sc * 128);            // bytes per head
    int boff = (s * 128 + lane * 2) ^ ((s & 7) << 4);          // swizzled layout
    *(unsigned short*)((char*)cbh + hbase + boff) = hi;
    *(unsigned short*)((char*)cbl + hbase + boff) = lo;
    float sq = val * val;
    #pragma unroll
    for (int off = 32; off; off >>= 1) sq += __shfl_xor(sq, off);
    if (lane == 0) c2[row] = sq;
}

// ---------------- fused kernel: 4 waves, 128 rows, 64-code chunks ----------------
__global__ __launch_bounds__(256, 6) void vq_mfma_kernel(
        const float* __restrict__ vecs,
        const float* __restrict__ c,
        const float* __restrict__ c2,
        const unsigned short* __restrict__ cbh,
        const unsigned short* __restrict__ cbl,
        const float* __restrict__ loss_mask,
        float* __restrict__ out_vh,
        float* __restrict__ out_z,
        float* __restrict__ out_err,
        float* __restrict__ partials) {
    __shared__ unsigned short bhi[64 * DKc];    // 8 KiB (swizzled content)
    __shared__ unsigned short blo[64 * DKc];    // 8 KiB
    __shared__ float c2_lds[Sc];                // 2 KiB
    __shared__ int2  top2s[128];                // 1 KiB -> 19.4 KiB total

    const int t   = threadIdx.x;
    const int l   = t & 63;
    const int w   = t >> 6;
    const int col = l & 15;
    const int ksl = l >> 4;

    // XCD head-affinity: consecutive-8 blocks round-robin XCDs; XCD i -> head i.
    const int flat = blockIdx.x;        // 0..2047
    const int h    = flat & 7;
    const int idx  = flat >> 3;         // 0..255
    const int b    = idx >> 5;
    const int lt   = idx & 31;          // 128-row tile
    const int bh   = b * Hc + h;

    const float* Avec  = vecs + ((size_t)bh * Lc + (size_t)lt * 128) * DKc;
    const float* Bp    = c + (size_t)h * Sc * DKc;
    const char*  cbh_h = (const char*)cbh + (size_t)h * (Sc * 128);
    const char*  cbl_h = (const char*)cbl + (size_t)h * (Sc * 128);

    // ---- chunk-0 staging loads (return under A-convert) ----
    u16x8 sph[2], spl[2];
    {
        const char* sh0 = cbh_h + w * 2048;
        const char* sl0 = cbl_h + w * 2048;
        #pragma unroll
        for (int i = 0; i < 2; ++i) {
            sph[i] = *(const u16x8*)(sh0 + i * 1024 + l * 16);
            spl[i] = *(const u16x8*)(sl0 + i * 1024 + l * 16);
        }
    }

    // ---- A fragments: rows w*32 + rt*16 + col; bf16 hi/lo in-reg ----
    bf16x8 fah[2][2], fal[2][2];
    #pragma unroll
    for (int rt = 0; rt < 2; ++rt) {
        const float* Ar = Avec + (size_t)((w << 5) + (rt << 4) + col) * DKc;
        #pragma unroll
        for (int ks = 0; ks < 2; ++ks) {
            int k0 = (ks << 5) + (ksl << 3);
            float4 p0 = *reinterpret_cast<const float4*>(Ar + k0);
            float4 p1 = *reinterpret_cast<const float4*>(Ar + k0 + 4);
            float e8[8] = {p0.x, p0.y, p0.z, p0.w, p1.x, p1.y, p1.z, p1.w};
            bf16x8 hv, lv;
            #pragma unroll
            for (int i = 0; i < 8; ++i) {
                unsigned short hi = f32_to_bf16_rne(e8[i]);
                hv[i] = (short)hi;
                lv[i] = (short)f32_to_bf16_rne(e8[i] - bf16_hi_f32(hi));
            }
            fah[rt][ks] = hv;
            fal[rt][ks] = lv;
        }
    }

    c2_lds[t]       = c2[h * Sc + t];
    c2_lds[t + 256] = c2[h * Sc + t + 256];

    // ---- write chunk 0 into LDS ----
    {
        char* dh = (char*)bhi + w * 2048;
        char* dl = (char*)blo + w * 2048;
        #pragma unroll
        for (int i = 0; i < 2; ++i) {
            *(u16x8*)(dh + i * 1024 + l * 16) = sph[i];
            *(u16x8*)(dl + i * 1024 + l * 16) = spl[i];
        }
    }
    __syncthreads();

    // per-lane top-2 MAX state over m = dot - c2/2; indices packed (i2<<16 | i1)
    float v1[2][4], v2[2][4];
    unsigned pk[2][4];
    #pragma unroll
    for (int rt = 0; rt < 2; ++rt)
        #pragma unroll
        for (int r = 0; r < 4; ++r) { v1[rt][r] = -3.0e38f; v2[rt][r] = -3.0e38f; pk[rt][r] = 0u; }

    for (int chunk = 0; chunk < 8; ++chunk) {
        // T14: issue next chunk's loads now; consumed after the read-barrier
        u16x8 nh[2], nl[2];
        if (chunk < 7) {
            const char* sh_ = cbh_h + ((chunk + 1) << 13) + w * 2048;
            const char* sl_ = cbl_h + ((chunk + 1) << 13) + w * 2048;
            #pragma unroll
            for (int i = 0; i < 2; ++i) {
                nh[i] = *(const u16x8*)(sh_ + i * 1024 + l * 16);
                nl[i] = *(const u16x8*)(sl_ + i * 1024 + l * 16);
            }
        }

        auto INIT = [&](int j, f32x4 (&a)[2]) {
            float m0 = -0.5f * c2_lds[(chunk << 6) + (j << 4) + col];
            a[0] = (f32x4){m0, m0, m0, m0};
            a[1] = (f32x4){m0, m0, m0, m0};
        };
        auto STEP = [&](int j, f32x4 (&acc)[2]) {
            int crow = (j << 4) + col;
            int o0 = ((crow << 7) + (ksl << 4)) ^ ((crow & 7) << 4);
            bf16x8 h0 = *reinterpret_cast<const bf16x8*>((const char*)bhi + o0);
            bf16x8 h1 = *reinterpret_cast<const bf16x8*>((const char*)bhi + (o0 ^ 64));
            bf16x8 g0 = *reinterpret_cast<const bf16x8*>((const char*)blo + o0);
            bf16x8 g1 = *reinterpret_cast<const bf16x8*>((const char*)blo + (o0 ^ 64));
            #pragma unroll
            for (int rt = 0; rt < 2; ++rt) {
                acc[rt] = __builtin_amdgcn_mfma_f32_16x16x32_bf16(fah[rt][0], h0, acc[rt], 0, 0, 0);
                acc[rt] = __builtin_amdgcn_mfma_f32_16x16x32_bf16(fah[rt][1], h1, acc[rt], 0, 0, 0);
                acc[rt] = __builtin_amdgcn_mfma_f32_16x16x32_bf16(fal[rt][0], h0, acc[rt], 0, 0, 0);
                acc[rt] = __builtin_amdgcn_mfma_f32_16x16x32_bf16(fal[rt][1], h1, acc[rt], 0, 0, 0);
                acc[rt] = __builtin_amdgcn_mfma_f32_16x16x32_bf16(fah[rt][0], g0, acc[rt], 0, 0, 0);
                acc[rt] = __builtin_amdgcn_mfma_f32_16x16x32_bf16(fah[rt][1], g1, acc[rt], 0, 0, 0);
            }
        };
        auto FOLD = [&](int j, f32x4 (&acc)[2]) {
            int code = (chunk << 6) + (j << 4) + col;
            unsigned scode = (unsigned)code << 16;
            #pragma unroll
            for (int rt = 0; rt < 2; ++rt)
                #pragma unroll
                for (int r = 0; r < 4; ++r) {
                    float m = acc[rt][r];
                    bool c1  = m > v1[rt][r];
                    bool c2b = m > v2[rt][r];
                    v2[rt][r] = fminf(fmaxf(m, v2[rt][r]), v1[rt][r]);   // med3
                    v1[rt][r] = fmaxf(v1[rt][r], m);
                    unsigned p  = pk[rt][r];
                    unsigned pa = (p << 16) | (unsigned)code;            // c1: i1'=code, i2'=old i1
                    unsigned pb = (p & 0xFFFFu) | scode;                 // c2b: i2'=code
                    pk[rt][r] = c1 ? pa : (c2b ? pb : p);
                }
        };

        // 2-slot rotation over the 4 sixteen-code tiles
        f32x4 accA[2], accB[2];
        INIT(0, accA); STEP(0, accA);
        INIT(1, accB); STEP(1, accB);
        FOLD(0, accA); INIT(2, accA); STEP(2, accA);
        FOLD(1, accB); INIT(3, accB); STEP(3, accB);
        FOLD(2, accA);
        FOLD(3, accB);

        __syncthreads();    // all waves done reading bhi/blo
        if (chunk < 7) {
            char* dh = (char*)bhi + w * 2048;
            char* dl = (char*)blo + w * 2048;
            #pragma unroll
            for (int i = 0; i < 2; ++i) {
                *(u16x8*)(dh + i * 1024 + l * 16) = nh[i];
                *(u16x8*)(dl + i * 1024 + l * 16) = nl[i];
            }
            __syncthreads();
        }
    }

    // ---- cross-lane top-2 merge (max) over the 16 cols sharing each row ----
    #pragma unroll
    for (int off = 1; off <= 8; off <<= 1) {
        #pragma unroll
        for (int rt = 0; rt < 2; ++rt)
            #pragma unroll
            for (int r = 0; r < 4; ++r) {
                float w1 = __shfl_xor(v1[rt][r], off);
                float w2 = __shfl_xor(v2[rt][r], off);
                unsigned q = (unsigned)__shfl_xor((int)pk[rt][r], off);
                int mi1 = (int)(pk[rt][r] & 0xFFFFu);
                int mi2 = (int)(pk[rt][r] >> 16);
                int j1  = (int)(q & 0xFFFFu);
                int j2  = (int)(q >> 16);
                bool firstWins = (w1 > v1[rt][r]) || (w1 == v1[rt][r] && j1 < mi1);
                if (firstWins) {
                    float nv2; int ni2;
                    if (v1[rt][r] > w2 || (v1[rt][r] == w2 && mi1 < j2)) { nv2 = v1[rt][r]; ni2 = mi1; }
                    else                                                 { nv2 = w2;        ni2 = j2; }
                    v1[rt][r] = w1; v2[rt][r] = nv2;
                    pk[rt][r] = ((unsigned)ni2 << 16) | (unsigned)j1;
                } else if (w1 > v2[rt][r] || (w1 == v2[rt][r] && j1 < mi2)) {
                    v2[rt][r] = w1;
                    pk[rt][r] = ((unsigned)j1 << 16) | (unsigned)mi1;
                }
            }
    }
    if (col == 0) {
        #pragma unroll
        for (int rt = 0; rt < 2; ++rt)
            #pragma unroll
            for (int r = 0; r < 4; ++r)
                top2s[(w << 5) + (rt << 4) + (ksl << 2) + r] =
                    make_int2((int)(pk[rt][r] & 0xFFFFu), (int)(pk[rt][r] >> 16));
    }
    __syncthreads();

    // ---- refine (2-pass, low-reg): 4 lanes/row; f64 delta decides; f32 err ----
    double macc = 0.0;
    #pragma unroll
    for (int rt = 0; rt < 2; ++rt) {
        int  rloc = (w << 5) + (rt << 4) + col;     // block-local row 0..127
        int  lrow = lt * 128 + rloc;
        long grow = (long)bh * Lc + lrow;
        int2 zz   = top2s[rloc];
        const float* Ar = Avec + (size_t)rloc * DKc;
        const float* C1 = Bp + (size_t)zz.x * DKc;
        const float* C2 = Bp + (size_t)zz.y * DKc;
        const int k0 = ksl << 3;
        // pass 1: dd = d1 - d2 = sum (c1-c2)*((c1+c2) - 2v), streamed per quad
        double dd = 0.0;
        #pragma unroll
        for (int q = 0; q < 4; ++q) {
            int ko = ((q >> 1) << 5) + ((q & 1) << 2) + k0;
            f32x4 va = *reinterpret_cast<const f32x4*>(Ar + ko);
            f32x4 ca = *reinterpret_cast<const f32x4*>(C1 + ko);
            f32x4 cb = *reinterpret_cast<const f32x4*>(C2 + ko);
            #pragma unroll
            for (int m = 0; m < 4; ++m) {
                double a = (double)ca[m], bb = (double)cb[m], vv = (double)va[m];
                dd = fma(a - bb, (a + bb) - 2.0 * vv, dd);
            }
        }
        dd += __shfl_xor(dd, 16);
        dd += __shfl_xor(dd, 32);
        bool second = (dd > 0.0) || (dd == 0.0 && zz.y < zz.x);
        int zsel = second ? zz.y : zz.x;
        const float* Cs = second ? C2 : C1;
        // pass 2: gather selected row, err, write
        float e = 0.f;
        float* Or = out_vh + (size_t)grow * DKc;
        #pragma unroll
        for (int q = 0; q < 4; ++q) {
            int ko = ((q >> 1) << 5) + ((q & 1) << 2) + k0;
            f32x4 va = *reinterpret_cast<const f32x4*>(Ar + ko);
            f32x4 cs = *reinterpret_cast<const f32x4*>(Cs + ko);
            #pragma unroll
            for (int m = 0; m < 4; ++m) {
                float td = va[m] - cs[m];
                e = fmaf(td, td, e);
            }
            *reinterpret_cast<f32x4*>(Or + ko) = cs;
        }
        e += __shfl_xor(e, 16);
        e += __shfl_xor(e, 32);
        if (ksl == 0) {
            out_z[grow]   = (float)zsel;
            out_err[grow] = e;
            macc += (double)loss_mask[b * Lc + lrow] * (double)e;
        }
    }
    #pragma unroll
    for (int off = 1; off <= 8; off <<= 1) macc += __shfl_xor(macc, off);
    if (l == 0) partials[flat * 4 + w] = (float)macc;
}

// ---------------- finalize ----------------
__global__ __launch_bounds__(256) void finalize_kernel(
        const float* __restrict__ partials, int n,
        float* __restrict__ out_lcommit, float* __restrict__ out_lcode) {
    __shared__ double sh[256];
    double a = 0.0;
    for (int i = threadIdx.x; i < n; i += 256) a += (double)partials[i];
    sh[threadIdx.x] = a;
    __syncthreads();
    for (int s = 128; s; s >>= 1) {
        if (threadIdx.x < s) sh[threadIdx.x] += sh[threadIdx.x + s];
        __syncthreads();
    }
    if (threadIdx.x == 0) {
        double lc = sh[0] / (double)(Bc * Lc);
        *out_lcommit = (float)lc;
        *out_lcode   = 0.0f;
    }
}

extern "C" void kernel_launch(void* const* d_in, const int* in_sizes, int n_in,
                              void* d_out, int out_size, void* d_ws, size_t ws_size,
                              hipStream_t stream) {
    const float* vecs      = (const float*)d_in[0];
    const float* c_sum     = (const float*)d_in[1];
    const float* c_count   = (const float*)d_in[2];
    const float* loss_mask = (const float*)d_in[3];
    (void)in_sizes; (void)n_in; (void)out_size; (void)ws_size;

    char* ws = (char*)d_ws;
    float*          c        = (float*)(ws + WS_C_OFF);
    float*          c2       = (float*)(ws + WS_C2_OFF);
    unsigned short* cbh      = (unsigned short*)(ws + WS_CBH_OFF);
    unsigned short* cbl      = (unsigned short*)(ws + WS_CBL_OFF);
    float*          partials = (float*)(ws + WS_PART_OFF);

    float* out = (float*)d_out;
    float* out_vh      = out;                                   // B*H*L*DK
    float* out_z       = out + (size_t)Bc * Hc * Lc * DKc;      // B*H*L
    float* out_lcommit = out_z + (size_t)Bc * Hc * Lc;          // 1
    float* out_lcode   = out_lcommit + 1;                       // 1
    float* out_err     = out_lcode + 1;                         // B*H*L

    prep_kernel<<<(Hc * Sc * 64) / 256, 256, 0, stream>>>(c_sum, c_count, c, c2, cbh, cbl);

    vq_mfma_kernel<<<2048, 256, 0, stream>>>(vecs, c, c2, cbh, cbl, loss_mask,
                                             out_vh, out_z, out_err, partials);

    finalize_kernel<<<1, 256, 0, stream>>>(partials, NPART, out_lcommit, out_lcode);
}

// Round 9
// 142.292 us; speedup vs baseline: 3.4129x; 3.4129x over previous
//
#include <hip/hip_runtime.h>
#include <hip/hip_bf16.h>

// LearnableVQ forward on MI355X — v6: r7 structure, de-spilled + dbuf + coalesced refine.
// B=8 H=8 L=4096 DK=64 S=512. Inputs f32; output f32, concatenated:
//   vecs_hat[B,H,L,DK] | z[B,H,L] | l_commit | l_codebook | errs2[B,H,L]
// v6 vs v7/v8: launch_bounds(256,4) [r8's (256,6) caused 1.5GB spill traffic];
// 64-code chunks double-buffered (1 barrier/chunk); 2x3 split MFMA chains;
// refine with 4-lanes-per-row fully-coalesced 64B stores [fixes r5-r8 write
// amplification, WRITE 160->~72MB]; packed top-2 indices; XCD head affinity.

#define Bc 8
#define Hc 8
#define Lc 4096
#define DKc 64
#define Sc 512

typedef __attribute__((ext_vector_type(8))) short bf16x8;
typedef __attribute__((ext_vector_type(8))) unsigned short u16x8;
typedef __attribute__((ext_vector_type(4))) float f32x4;

// ---------------- ws layout (bytes) ----------------
#define WS_C_OFF    0u          // H*S*DK f32           = 1,048,576
#define WS_C2_OFF   1048576u    // H*S f32              =    16,384
#define WS_CBH_OFF  1064960u    // H*S*DK bf16 hi (swz) =   524,288
#define WS_CBL_OFF  1589248u    // H*S*DK bf16 lo (swz) =   524,288
#define WS_PART_OFF 2113536u    // 8192 f32             =    32,768
#define NPART       8192

__device__ __forceinline__ unsigned short f32_to_bf16_rne(float x) {
    unsigned u = __float_as_uint(x);
    unsigned r = (u + 0x7FFFu + ((u >> 16) & 1u)) >> 16;
    return (unsigned short)r;
}
__device__ __forceinline__ float bf16_hi_f32(unsigned short h) {
    return __uint_as_float(((unsigned)h) << 16);
}

// ---------------- prep: normalize codebook; c2; pre-split pre-swizzled bf16 ----------------
__global__ __launch_bounds__(256) void prep_kernel(
        const float* __restrict__ c_sum,
        const float* __restrict__ c_count,
        float* __restrict__ c,
        float* __restrict__ c2,
        unsigned short* __restrict__ cbh,
        unsigned short* __restrict__ cbl) {
    int row  = (blockIdx.x * blockDim.x + threadIdx.x) >> 6;   // h*512 + s
    int lane = threadIdx.x & 63;
    float cnt = c_count[row];
    float inv = 1.0f / fmaxf(cnt, 0.01f);
    float val = c_sum[row * DKc + lane] * inv;
    c[row * DKc + lane] = val;
    unsigned short hi = f32_to_bf16_rne(val);
    unsigned short lo = f32_to_bf16_rne(val - bf16_hi_f32(hi));
    int s = row & (Sc - 1);
    size_t hbase = (size_t)(row >> 9) * (Sc * 128);            // bytes per head
    int boff = (s * 128 + lane * 2) ^ ((s & 7) << 4);          // swizzled layout
    *(unsigned short*)((char*)cbh + hbase + boff) = hi;
    *(unsigned short*)((char*)cbl + hbase + boff) = lo;
    float sq = val * val;
    #pragma unroll
    for (int off = 32; off; off >>= 1) sq += __shfl_xor(sq, off);
    if (lane == 0) c2[row] = sq;
}

// ---------------- fused kernel: 4 waves, 128 rows, dbuf 64-code chunks ----------------
__global__ __launch_bounds__(256, 4) void vq_mfma_kernel(
        const float* __restrict__ vecs,
        const float* __restrict__ c,
        const float* __restrict__ c2,
        const unsigned short* __restrict__ cbh,
        const unsigned short* __restrict__ cbl,
        const float* __restrict__ loss_mask,
        float* __restrict__ out_vh,
        float* __restrict__ out_z,
        float* __restrict__ out_err,
        float* __restrict__ partials) {
    __shared__ unsigned short bhi[2][64 * DKc];   // 2 x 8 KiB (swizzled content)
    __shared__ unsigned short blo[2][64 * DKc];   // 2 x 8 KiB
    __shared__ float c2_lds[Sc];                  // 2 KiB
    __shared__ int2  top2s[128];                  // 1 KiB -> 35.3 KiB total

    const int t   = threadIdx.x;
    const int l   = t & 63;
    const int w   = t >> 6;
    const int col = l & 15;
    const int ksl = l >> 4;

    // XCD head-affinity: consecutive-8 blocks round-robin XCDs; XCD i -> head i.
    const int flat = blockIdx.x;        // 0..2047
    const int h    = flat & 7;
    const int idx  = flat >> 3;         // 0..255
    const int b    = idx >> 5;
    const int lt   = idx & 31;          // 128-row tile
    const int bh   = b * Hc + h;

    const float* Avec  = vecs + ((size_t)bh * Lc + (size_t)lt * 128) * DKc;
    const float* Bp    = c + (size_t)h * Sc * DKc;
    const char*  cbh_h = (const char*)cbh + (size_t)h * (Sc * 128);
    const char*  cbl_h = (const char*)cbl + (size_t)h * (Sc * 128);

    // ---- issue chunk-0 staging loads (return under A-convert) ----
    u16x8 nh[2], nl[2];
    {
        const char* sh0 = cbh_h + w * 2048;
        const char* sl0 = cbl_h + w * 2048;
        #pragma unroll
        for (int i = 0; i < 2; ++i) {
            nh[i] = *(const u16x8*)(sh0 + i * 1024 + l * 16);
            nl[i] = *(const u16x8*)(sl0 + i * 1024 + l * 16);
        }
    }

    // ---- A fragments: rows w*32 + rt*16 + col; bf16 hi/lo in-reg ----
    bf16x8 fah[2][2], fal[2][2];
    #pragma unroll
    for (int rt = 0; rt < 2; ++rt) {
        const float* Ar = Avec + (size_t)((w << 5) + (rt << 4) + col) * DKc;
        #pragma unroll
        for (int ks = 0; ks < 2; ++ks) {
            int k0 = (ks << 5) + (ksl << 3);
            float4 p0 = *reinterpret_cast<const float4*>(Ar + k0);
            float4 p1 = *reinterpret_cast<const float4*>(Ar + k0 + 4);
            float e8[8] = {p0.x, p0.y, p0.z, p0.w, p1.x, p1.y, p1.z, p1.w};
            bf16x8 hv, lv;
            #pragma unroll
            for (int i = 0; i < 8; ++i) {
                unsigned short hi = f32_to_bf16_rne(e8[i]);
                hv[i] = (short)hi;
                lv[i] = (short)f32_to_bf16_rne(e8[i] - bf16_hi_f32(hi));
            }
            fah[rt][ks] = hv;
            fal[rt][ks] = lv;
        }
    }

    c2_lds[t]       = c2[h * Sc + t];
    c2_lds[t + 256] = c2[h * Sc + t + 256];

    // ---- write chunk 0 into buffer 0 ----
    {
        char* dh = (char*)bhi[0] + w * 2048;
        char* dl = (char*)blo[0] + w * 2048;
        #pragma unroll
        for (int i = 0; i < 2; ++i) {
            *(u16x8*)(dh + i * 1024 + l * 16) = nh[i];
            *(u16x8*)(dl + i * 1024 + l * 16) = nl[i];
        }
    }
    __syncthreads();

    // per-lane top-2 MAX state over m = dot - c2/2; indices packed (i2<<16 | i1)
    float v1[2][4], v2[2][4];
    unsigned pk[2][4];
    #pragma unroll
    for (int rt = 0; rt < 2; ++rt)
        #pragma unroll
        for (int r = 0; r < 4; ++r) { v1[rt][r] = -3.0e38f; v2[rt][r] = -3.0e38f; pk[rt][r] = 0u; }

    for (int chunk = 0; chunk < 8; ++chunk) {
        // T14: issue next chunk's loads now; written to the idle buffer at chunk end
        if (chunk < 7) {
            const char* sh_ = cbh_h + ((chunk + 1) << 13) + w * 2048;
            const char* sl_ = cbl_h + ((chunk + 1) << 13) + w * 2048;
            #pragma unroll
            for (int i = 0; i < 2; ++i) {
                nh[i] = *(const u16x8*)(sh_ + i * 1024 + l * 16);
                nl[i] = *(const u16x8*)(sl_ + i * 1024 + l * 16);
            }
        }
        const char* ph = (const char*)bhi[chunk & 1];
        const char* pl = (const char*)blo[chunk & 1];

        // 2x3 split chains: cA = fah0*h0 + fah1*h1 + fah0*g0 ; cB = fal0*h0 + fal1*h1 + fah1*g1
        auto INIT = [&](int j, f32x4 (&cA)[2], f32x4 (&cB)[2]) {
            float m0 = -0.5f * c2_lds[(chunk << 6) + (j << 4) + col];
            cA[0] = (f32x4){m0, m0, m0, m0};
            cA[1] = (f32x4){m0, m0, m0, m0};
            cB[0] = (f32x4){0.f, 0.f, 0.f, 0.f};
            cB[1] = (f32x4){0.f, 0.f, 0.f, 0.f};
        };
        auto STEP = [&](int j, f32x4 (&cA)[2], f32x4 (&cB)[2]) {
            int crow = (j << 4) + col;
            int o0 = ((crow << 7) + (ksl << 4)) ^ ((crow & 7) << 4);
            bf16x8 h0 = *reinterpret_cast<const bf16x8*>(ph + o0);
            bf16x8 h1 = *reinterpret_cast<const bf16x8*>(ph + (o0 ^ 64));
            bf16x8 g0 = *reinterpret_cast<const bf16x8*>(pl + o0);
            bf16x8 g1 = *reinterpret_cast<const bf16x8*>(pl + (o0 ^ 64));
            #pragma unroll
            for (int rt = 0; rt < 2; ++rt) {
                cA[rt] = __builtin_amdgcn_mfma_f32_16x16x32_bf16(fah[rt][0], h0, cA[rt], 0, 0, 0);
                cB[rt] = __builtin_amdgcn_mfma_f32_16x16x32_bf16(fal[rt][0], h0, cB[rt], 0, 0, 0);
                cA[rt] = __builtin_amdgcn_mfma_f32_16x16x32_bf16(fah[rt][1], h1, cA[rt], 0, 0, 0);
                cB[rt] = __builtin_amdgcn_mfma_f32_16x16x32_bf16(fal[rt][1], h1, cB[rt], 0, 0, 0);
                cA[rt] = __builtin_amdgcn_mfma_f32_16x16x32_bf16(fah[rt][0], g0, cA[rt], 0, 0, 0);
                cB[rt] = __builtin_amdgcn_mfma_f32_16x16x32_bf16(fah[rt][1], g1, cB[rt], 0, 0, 0);
            }
        };
        auto FOLD = [&](int j, f32x4 (&cA)[2], f32x4 (&cB)[2]) {
            int code = (chunk << 6) + (j << 4) + col;
            unsigned scode = (unsigned)code << 16;
            #pragma unroll
            for (int rt = 0; rt < 2; ++rt)
                #pragma unroll
                for (int r = 0; r < 4; ++r) {
                    float m = cA[rt][r] + cB[rt][r];
                    bool b1  = m > v1[rt][r];
                    bool b2  = m > v2[rt][r];
                    v2[rt][r] = fminf(fmaxf(m, v2[rt][r]), v1[rt][r]);   // med3
                    v1[rt][r] = fmaxf(v1[rt][r], m);
                    unsigned p  = pk[rt][r];
                    unsigned pa = (p << 16) | (unsigned)code;            // b1: i1'=code, i2'=old i1
                    unsigned pb = (p & 0xFFFFu) | scode;                 // b2: i2'=code
                    pk[rt][r] = b1 ? pa : (b2 ? pb : p);
                }
        };

        // 2-slot rotation over the 4 sixteen-code tiles
        f32x4 sA0[2], sB0[2], sA1[2], sB1[2];
        INIT(0, sA0, sB0); STEP(0, sA0, sB0);
        INIT(1, sA1, sB1); STEP(1, sA1, sB1);
        FOLD(0, sA0, sB0); INIT(2, sA0, sB0); STEP(2, sA0, sB0);
        FOLD(1, sA1, sB1); INIT(3, sA1, sB1); STEP(3, sA1, sB1);
        FOLD(2, sA0, sB0);
        FOLD(3, sA1, sB1);

        if (chunk < 7) {
            // write NEXT chunk into the idle buffer; prior reads of it finished
            // before the previous barrier, so one barrier per chunk suffices.
            char* dh = (char*)bhi[(chunk + 1) & 1] + w * 2048;
            char* dl = (char*)blo[(chunk + 1) & 1] + w * 2048;
            #pragma unroll
            for (int i = 0; i < 2; ++i) {
                *(u16x8*)(dh + i * 1024 + l * 16) = nh[i];
                *(u16x8*)(dl + i * 1024 + l * 16) = nl[i];
            }
            __syncthreads();
        }
    }

    // ---- cross-lane top-2 merge (max) over the 16 cols sharing each row ----
    #pragma unroll
    for (int off = 1; off <= 8; off <<= 1) {
        #pragma unroll
        for (int rt = 0; rt < 2; ++rt)
            #pragma unroll
            for (int r = 0; r < 4; ++r) {
                float w1 = __shfl_xor(v1[rt][r], off);
                float w2 = __shfl_xor(v2[rt][r], off);
                unsigned q = (unsigned)__shfl_xor((int)pk[rt][r], off);
                int mi1 = (int)(pk[rt][r] & 0xFFFFu);
                int mi2 = (int)(pk[rt][r] >> 16);
                int j1  = (int)(q & 0xFFFFu);
                int j2  = (int)(q >> 16);
                bool firstWins = (w1 > v1[rt][r]) || (w1 == v1[rt][r] && j1 < mi1);
                if (firstWins) {
                    float nv2; int ni2;
                    if (v1[rt][r] > w2 || (v1[rt][r] == w2 && mi1 < j2)) { nv2 = v1[rt][r]; ni2 = mi1; }
                    else                                                 { nv2 = w2;        ni2 = j2; }
                    v1[rt][r] = w1; v2[rt][r] = nv2;
                    pk[rt][r] = ((unsigned)ni2 << 16) | (unsigned)j1;
                } else if (w1 > v2[rt][r] || (w1 == v2[rt][r] && j1 < mi2)) {
                    v2[rt][r] = w1;
                    pk[rt][r] = ((unsigned)j1 << 16) | (unsigned)mi1;
                }
            }
    }
    if (col == 0) {
        #pragma unroll
        for (int rt = 0; rt < 2; ++rt)
            #pragma unroll
            for (int r = 0; r < 4; ++r)
                top2s[(w << 5) + (rt << 4) + (ksl << 2) + r] =
                    make_int2((int)(pk[rt][r] & 0xFFFFu), (int)(pk[rt][r] >> 16));
    }
    __syncthreads();

    // ---- refine: 4 lanes per row (lane owns floats qo..qo+3 of each 16-float
    //      quad-group) -> fully coalesced 64B stores. f64 delta decides z. ----
    const int rl = l >> 2;              // row within 16-row group
    const int qo = (l & 3) << 2;        // float offset within 16-float group
    double macc = 0.0;
    #pragma unroll
    for (int rt = 0; rt < 2; ++rt) {
        int  rloc = (w << 5) + (rt << 4) + rl;      // block-local row 0..127
        int  lrow = lt * 128 + rloc;
        long grow = (long)bh * Lc + lrow;
        int2 zz   = top2s[rloc];
        const float* Ar = Avec + (size_t)rloc * DKc;
        const float* C1 = Bp + (size_t)zz.x * DKc;
        const float* C2 = Bp + (size_t)zz.y * DKc;
        // pass 1: dd = d1 - d2 = sum (c1-c2)*((c1+c2) - 2v)
        double dd = 0.0;
        #pragma unroll
        for (int q = 0; q < 4; ++q) {
            int ko = (q << 4) + qo;
            f32x4 va = *reinterpret_cast<const f32x4*>(Ar + ko);
            f32x4 ca = *reinterpret_cast<const f32x4*>(C1 + ko);
            f32x4 cb = *reinterpret_cast<const f32x4*>(C2 + ko);
            #pragma unroll
            for (int m = 0; m < 4; ++m) {
                double a = (double)ca[m], bb = (double)cb[m], vv = (double)va[m];
                dd = fma(a - bb, (a + bb) - 2.0 * vv, dd);
            }
        }
        dd += __shfl_xor(dd, 1);
        dd += __shfl_xor(dd, 2);
        bool second = (dd > 0.0) || (dd == 0.0 && zz.y < zz.x);
        int zsel = second ? zz.y : zz.x;
        const float* Cs = second ? C2 : C1;
        // pass 2: gather selected row, err, coalesced write
        float e = 0.f;
        float* Or = out_vh + (size_t)grow * DKc;
        #pragma unroll
        for (int q = 0; q < 4; ++q) {
            int ko = (q << 4) + qo;
            f32x4 va = *reinterpret_cast<const f32x4*>(Ar + ko);
            f32x4 cs = *reinterpret_cast<const f32x4*>(Cs + ko);
            #pragma unroll
            for (int m = 0; m < 4; ++m) {
                float td = va[m] - cs[m];
                e = fmaf(td, td, e);
            }
            *reinterpret_cast<f32x4*>(Or + ko) = cs;
        }
        e += __shfl_xor(e, 1);
        e += __shfl_xor(e, 2);
        if ((l & 3) == 0) {
            out_z[grow]   = (float)zsel;
            out_err[grow] = e;
            macc += (double)loss_mask[b * Lc + lrow] * (double)e;
        }
    }
    #pragma unroll
    for (int off = 1; off <= 32; off <<= 1) macc += __shfl_xor(macc, off);
    if (l == 0) partials[flat * 4 + w] = (float)macc;
}

// ---------------- finalize ----------------
__global__ __launch_bounds__(256) void finalize_kernel(
        const float* __restrict__ partials, int n,
        float* __restrict__ out_lcommit, float* __restrict__ out_lcode) {
    __shared__ double sh[256];
    double a = 0.0;
    for (int i = threadIdx.x; i < n; i += 256) a += (double)partials[i];
    sh[threadIdx.x] = a;
    __syncthreads();
    for (int s = 128; s; s >>= 1) {
        if (threadIdx.x < s) sh[threadIdx.x] += sh[threadIdx.x + s];
        __syncthreads();
    }
    if (threadIdx.x == 0) {
        double lc = sh[0] / (double)(Bc * Lc);
        *out_lcommit = (float)lc;
        *out_lcode   = 0.0f;
    }
}

extern "C" void kernel_launch(void* const* d_in, const int* in_sizes, int n_in,
                              void* d_out, int out_size, void* d_ws, size_t ws_size,
                              hipStream_t stream) {
    const float* vecs      = (const float*)d_in[0];
    const float* c_sum     = (const float*)d_in[1];
    const float* c_count   = (const float*)d_in[2];
    const float* loss_mask = (const float*)d_in[3];
    (void)in_sizes; (void)n_in; (void)out_size; (void)ws_size;

    char* ws = (char*)d_ws;
    float*          c        = (float*)(ws + WS_C_OFF);
    float*          c2       = (float*)(ws + WS_C2_OFF);
    unsigned short* cbh      = (unsigned short*)(ws + WS_CBH_OFF);
    unsigned short* cbl      = (unsigned short*)(ws + WS_CBL_OFF);
    float*          partials = (float*)(ws + WS_PART_OFF);

    float* out = (float*)d_out;
    float* out_vh      = out;                                   // B*H*L*DK
    float* out_z       = out + (size_t)Bc * Hc * Lc * DKc;      // B*H*L
    float* out_lcommit = out_z + (size_t)Bc * Hc * Lc;          // 1
    float* out_lcode   = out_lcommit + 1;                       // 1
    float* out_err     = out_lcode + 1;                         // B*H*L

    prep_kernel<<<(Hc * Sc * 64) / 256, 256, 0, stream>>>(c_sum, c_count, c, c2, cbh, cbl);

    vq_mfma_kernel<<<2048, 256, 0, stream>>>(vecs, c, c2, cbh, cbl, loss_mask,
                                             out_vh, out_z, out_err, partials);

    finalize_kernel<<<1, 256, 0, stream>>>(partials, NPART, out_lcommit, out_lcode);
}

// Round 10
// 103.296 us; speedup vs baseline: 4.7013x; 1.3775x over previous
//
#include <hip/hip_runtime.h>
#include <hip/hip_bf16.h>

// LearnableVQ forward on MI355X — v7: sortable-key top-2 fold, gated f64 refine,
// full-line coalesced stores. B=8 H=8 L=4096 DK=64 S=512. Inputs f32; output f32:
//   vecs_hat[B,H,L,DK] | z[B,H,L] | l_commit | l_codebook | errs2[B,H,L]
// v7 vs v6: FOLD uses monotone u32 keys (value<<9 | (511-code)) -> max+med3,
// 7 inst/elem; key-based cross-lane merge; refine's f64 delta runs only when
// key-gap < tau (covers MFMA-split ~1e-3 + key-trunc ~4e-3 errors, 10x margin);
// refine uses 16 lanes/row -> 1KB-contiguous stores (fixes write amplification).

#define Bc 8
#define Hc 8
#define Lc 4096
#define DKc 64
#define Sc 512

typedef __attribute__((ext_vector_type(8))) short bf16x8;
typedef __attribute__((ext_vector_type(8))) unsigned short u16x8;
typedef __attribute__((ext_vector_type(4))) float f32x4;

// ---------------- ws layout (bytes) ----------------
#define WS_C_OFF    0u          // H*S*DK f32           = 1,048,576
#define WS_C2_OFF   1048576u    // H*S f32              =    16,384
#define WS_CBH_OFF  1064960u    // H*S*DK bf16 hi (swz) =   524,288
#define WS_CBL_OFF  1589248u    // H*S*DK bf16 lo (swz) =   524,288
#define WS_PART_OFF 2113536u    // 8192 f32             =    32,768
#define NPART       8192

__device__ __forceinline__ unsigned short f32_to_bf16_rne(float x) {
    unsigned u = __float_as_uint(x);
    unsigned r = (u + 0x7FFFu + ((u >> 16) & 1u)) >> 16;
    return (unsigned short)r;
}
__device__ __forceinline__ float bf16_hi_f32(unsigned short h) {
    return __uint_as_float(((unsigned)h) << 16);
}

// ---------------- prep: normalize codebook; c2; pre-split pre-swizzled bf16 ----------------
__global__ __launch_bounds__(256) void prep_kernel(
        const float* __restrict__ c_sum,
        const float* __restrict__ c_count,
        float* __restrict__ c,
        float* __restrict__ c2,
        unsigned short* __restrict__ cbh,
        unsigned short* __restrict__ cbl) {
    int row  = (blockIdx.x * blockDim.x + threadIdx.x) >> 6;   // h*512 + s
    int lane = threadIdx.x & 63;
    float cnt = c_count[row];
    float inv = 1.0f / fmaxf(cnt, 0.01f);
    float val = c_sum[row * DKc + lane] * inv;
    c[row * DKc + lane] = val;
    unsigned short hi = f32_to_bf16_rne(val);
    unsigned short lo = f32_to_bf16_rne(val - bf16_hi_f32(hi));
    int s = row & (Sc - 1);
    size_t hbase = (size_t)(row >> 9) * (Sc * 128);            // bytes per head
    int boff = (s * 128 + lane * 2) ^ ((s & 7) << 4);          // swizzled layout
    *(unsigned short*)((char*)cbh + hbase + boff) = hi;
    *(unsigned short*)((char*)cbl + hbase + boff) = lo;
    float sq = val * val;
    #pragma unroll
    for (int off = 32; off; off >>= 1) sq += __shfl_xor(sq, off);
    if (lane == 0) c2[row] = sq;
}

// ---------------- fused kernel: 4 waves, 128 rows, dbuf 64-code chunks ----------------
__global__ __launch_bounds__(256, 4) void vq_mfma_kernel(
        const float* __restrict__ vecs,
        const float* __restrict__ c,
        const float* __restrict__ c2,
        const unsigned short* __restrict__ cbh,
        const unsigned short* __restrict__ cbl,
        const float* __restrict__ loss_mask,
        float* __restrict__ out_vh,
        float* __restrict__ out_z,
        float* __restrict__ out_err,
        float* __restrict__ partials) {
    __shared__ unsigned short bhi[2][64 * DKc];   // 2 x 8 KiB (swizzled content)
    __shared__ unsigned short blo[2][64 * DKc];   // 2 x 8 KiB
    __shared__ float c2_lds[Sc];                  // 2 KiB
    __shared__ int2  top2s[128];                  // 1 KiB -> 35.3 KiB total

    const int t   = threadIdx.x;
    const int l   = t & 63;
    const int w   = t >> 6;
    const int col = l & 15;
    const int ksl = l >> 4;

    // XCD head-affinity: consecutive-8 blocks round-robin XCDs; XCD i -> head i.
    const int flat = blockIdx.x;        // 0..2047
    const int h    = flat & 7;
    const int idx  = flat >> 3;         // 0..255
    const int b    = idx >> 5;
    const int lt   = idx & 31;          // 128-row tile
    const int bh   = b * Hc + h;

    const float* Avec  = vecs + ((size_t)bh * Lc + (size_t)lt * 128) * DKc;
    const float* Bp    = c + (size_t)h * Sc * DKc;
    const char*  cbh_h = (const char*)cbh + (size_t)h * (Sc * 128);
    const char*  cbl_h = (const char*)cbl + (size_t)h * (Sc * 128);

    // ---- issue chunk-0 staging loads (return under A-convert) ----
    u16x8 nh[2], nl[2];
    {
        const char* sh0 = cbh_h + w * 2048;
        const char* sl0 = cbl_h + w * 2048;
        #pragma unroll
        for (int i = 0; i < 2; ++i) {
            nh[i] = *(const u16x8*)(sh0 + i * 1024 + l * 16);
            nl[i] = *(const u16x8*)(sl0 + i * 1024 + l * 16);
        }
    }

    // ---- A fragments: rows w*32 + rt*16 + col; bf16 hi/lo in-reg ----
    bf16x8 fah[2][2], fal[2][2];
    #pragma unroll
    for (int rt = 0; rt < 2; ++rt) {
        const float* Ar = Avec + (size_t)((w << 5) + (rt << 4) + col) * DKc;
        #pragma unroll
        for (int ks = 0; ks < 2; ++ks) {
            int k0 = (ks << 5) + (ksl << 3);
            float4 p0 = *reinterpret_cast<const float4*>(Ar + k0);
            float4 p1 = *reinterpret_cast<const float4*>(Ar + k0 + 4);
            float e8[8] = {p0.x, p0.y, p0.z, p0.w, p1.x, p1.y, p1.z, p1.w};
            bf16x8 hv, lv;
            #pragma unroll
            for (int i = 0; i < 8; ++i) {
                unsigned short hi = f32_to_bf16_rne(e8[i]);
                hv[i] = (short)hi;
                lv[i] = (short)f32_to_bf16_rne(e8[i] - bf16_hi_f32(hi));
            }
            fah[rt][ks] = hv;
            fal[rt][ks] = lv;
        }
    }

    c2_lds[t]       = c2[h * Sc + t];
    c2_lds[t + 256] = c2[h * Sc + t + 256];

    // ---- write chunk 0 into buffer 0 ----
    {
        char* dh = (char*)bhi[0] + w * 2048;
        char* dl = (char*)blo[0] + w * 2048;
        #pragma unroll
        for (int i = 0; i < 2; ++i) {
            *(u16x8*)(dh + i * 1024 + l * 16) = nh[i];
            *(u16x8*)(dl + i * 1024 + l * 16) = nl[i];
        }
    }
    __syncthreads();

    // per-lane top-2 over monotone keys: key = mono(m) & ~0x1FF | (511-code)
    unsigned v1k[2][4], v2k[2][4];
    #pragma unroll
    for (int rt = 0; rt < 2; ++rt)
        #pragma unroll
        for (int r = 0; r < 4; ++r) { v1k[rt][r] = 0u; v2k[rt][r] = 0u; }

    for (int chunk = 0; chunk < 8; ++chunk) {
        // T14: issue next chunk's loads now; written to the idle buffer at chunk end
        if (chunk < 7) {
            const char* sh_ = cbh_h + ((chunk + 1) << 13) + w * 2048;
            const char* sl_ = cbl_h + ((chunk + 1) << 13) + w * 2048;
            #pragma unroll
            for (int i = 0; i < 2; ++i) {
                nh[i] = *(const u16x8*)(sh_ + i * 1024 + l * 16);
                nl[i] = *(const u16x8*)(sl_ + i * 1024 + l * 16);
            }
        }
        const char* ph = (const char*)bhi[chunk & 1];
        const char* pl = (const char*)blo[chunk & 1];

        auto INIT = [&](int j, f32x4 (&cA)[2], f32x4 (&cB)[2]) {
            float m0 = -0.5f * c2_lds[(chunk << 6) + (j << 4) + col];
            cA[0] = (f32x4){m0, m0, m0, m0};
            cA[1] = (f32x4){m0, m0, m0, m0};
            cB[0] = (f32x4){0.f, 0.f, 0.f, 0.f};
            cB[1] = (f32x4){0.f, 0.f, 0.f, 0.f};
        };
        auto STEP = [&](int j, f32x4 (&cA)[2], f32x4 (&cB)[2]) {
            int crow = (j << 4) + col;
            int o0 = ((crow << 7) + (ksl << 4)) ^ ((crow & 7) << 4);
            bf16x8 h0 = *reinterpret_cast<const bf16x8*>(ph + o0);
            bf16x8 h1 = *reinterpret_cast<const bf16x8*>(ph + (o0 ^ 64));
            bf16x8 g0 = *reinterpret_cast<const bf16x8*>(pl + o0);
            bf16x8 g1 = *reinterpret_cast<const bf16x8*>(pl + (o0 ^ 64));
            #pragma unroll
            for (int rt = 0; rt < 2; ++rt) {
                cA[rt] = __builtin_amdgcn_mfma_f32_16x16x32_bf16(fah[rt][0], h0, cA[rt], 0, 0, 0);
                cB[rt] = __builtin_amdgcn_mfma_f32_16x16x32_bf16(fal[rt][0], h0, cB[rt], 0, 0, 0);
                cA[rt] = __builtin_amdgcn_mfma_f32_16x16x32_bf16(fah[rt][1], h1, cA[rt], 0, 0, 0);
                cB[rt] = __builtin_amdgcn_mfma_f32_16x16x32_bf16(fal[rt][1], h1, cB[rt], 0, 0, 0);
                cA[rt] = __builtin_amdgcn_mfma_f32_16x16x32_bf16(fah[rt][0], g0, cA[rt], 0, 0, 0);
                cB[rt] = __builtin_amdgcn_mfma_f32_16x16x32_bf16(fah[rt][1], g1, cB[rt], 0, 0, 0);
            }
        };
        auto FOLD = [&](int j, f32x4 (&cA)[2], f32x4 (&cB)[2]) {
            unsigned invc = 511u - (unsigned)((chunk << 6) + (j << 4) + col);
            #pragma unroll
            for (int rt = 0; rt < 2; ++rt)
                #pragma unroll
                for (int r = 0; r < 4; ++r) {
                    float m = cA[rt][r] + cB[rt][r];
                    unsigned bits = __float_as_uint(m);
                    unsigned mask = ((unsigned)((int)bits >> 31)) | 0x80000000u;
                    unsigned key  = ((bits ^ mask) & ~0x1FFu) | invc;
                    v2k[rt][r] = min(max(key, v2k[rt][r]), v1k[rt][r]);  // med3 pattern
                    v1k[rt][r] = max(v1k[rt][r], key);
                }
        };

        // 2-slot rotation over the 4 sixteen-code tiles
        f32x4 sA0[2], sB0[2], sA1[2], sB1[2];
        INIT(0, sA0, sB0); STEP(0, sA0, sB0);
        INIT(1, sA1, sB1); STEP(1, sA1, sB1);
        FOLD(0, sA0, sB0); INIT(2, sA0, sB0); STEP(2, sA0, sB0);
        FOLD(1, sA1, sB1); INIT(3, sA1, sB1); STEP(3, sA1, sB1);
        FOLD(2, sA0, sB0);
        FOLD(3, sA1, sB1);

        if (chunk < 7) {
            char* dh = (char*)bhi[(chunk + 1) & 1] + w * 2048;
            char* dl = (char*)blo[(chunk + 1) & 1] + w * 2048;
            #pragma unroll
            for (int i = 0; i < 2; ++i) {
                *(u16x8*)(dh + i * 1024 + l * 16) = nh[i];
                *(u16x8*)(dl + i * 1024 + l * 16) = nl[i];
            }
            __syncthreads();
        }
    }

    // ---- cross-lane top-2 merge over the 16 cols sharing each row (keys) ----
    #pragma unroll
    for (int off = 1; off <= 8; off <<= 1) {
        #pragma unroll
        for (int rt = 0; rt < 2; ++rt)
            #pragma unroll
            for (int r = 0; r < 4; ++r) {
                unsigned o1 = (unsigned)__shfl_xor((int)v1k[rt][r], off);
                unsigned o2 = (unsigned)__shfl_xor((int)v2k[rt][r], off);
                unsigned lo = min(v1k[rt][r], o1);
                v1k[rt][r]  = max(v1k[rt][r], o1);
                v2k[rt][r]  = max(lo, max(v2k[rt][r], o2));
            }
    }
    if (col == 0) {
        #pragma unroll
        for (int rt = 0; rt < 2; ++rt)
            #pragma unroll
            for (int r = 0; r < 4; ++r) {
                unsigned k1 = v1k[rt][r], k2 = v2k[rt][r];
                int z1 = 511 - (int)(k1 & 0x1FFu);
                int z2 = 511 - (int)(k2 & 0x1FFu);
                // approx values back from truncated keys; gate the f64 refine
                unsigned vb1 = k1 & ~0x1FFu, vb2 = k2 & ~0x1FFu;
                unsigned bb1 = (vb1 & 0x80000000u) ? (vb1 ^ 0x80000000u) : ~vb1;
                unsigned bb2 = (vb2 & 0x80000000u) ? (vb2 ^ 0x80000000u) : ~vb2;
                float gap = __uint_as_float(bb1) - __uint_as_float(bb2);
                bool need = gap < 0.05f;    // tau >> (MFMA-split ~1e-3 + trunc ~4e-3)
                top2s[(w << 5) + (rt << 4) + (ksl << 2) + r] = make_int2(z1, need ? z2 : z1);
            }
    }
    __syncthreads();

    // ---- refine: 16 lanes/row, 4 rows/iter (1KB contiguous stores);
    //      f64 delta only when top-2 genuinely close ----
    const int qo = (l & 15) << 2;       // float offset within row
    const int rq = l >> 4;              // row within 4-row group
    double macc = 0.0;
    #pragma unroll
    for (int it = 0; it < 8; ++it) {
        int  rloc = (w << 5) + (it << 2) + rq;      // block-local row 0..127
        int  lrow = lt * 128 + rloc;
        long grow = (long)bh * Lc + lrow;
        int2 zz   = top2s[rloc];
        const float* Ar = Avec + (size_t)rloc * DKc;
        const float* C1 = Bp + (size_t)zz.x * DKc;
        const float* C2 = Bp + (size_t)zz.y * DKc;
        f32x4 va = *reinterpret_cast<const f32x4*>(Ar + qo);
        f32x4 ca = *reinterpret_cast<const f32x4*>(C1 + qo);
        f32x4 cb = *reinterpret_cast<const f32x4*>(C2 + qo);
        double dd = 0.0;                // d1 - d2 = sum (c1-c2)*((c1+c2) - 2v)
        if (zz.x != zz.y) {             // uniform across the row's 16 lanes
            #pragma unroll
            for (int m = 0; m < 4; ++m) {
                double a = (double)ca[m], bb = (double)cb[m], vv = (double)va[m];
                dd = fma(a - bb, (a + bb) - 2.0 * vv, dd);
            }
            dd += __shfl_xor(dd, 1);
            dd += __shfl_xor(dd, 2);
            dd += __shfl_xor(dd, 4);
            dd += __shfl_xor(dd, 8);
        }
        bool second = (dd > 0.0) || (dd == 0.0 && zz.y < zz.x);
        int zsel = second ? zz.y : zz.x;
        f32x4 cs = second ? cb : ca;
        float e = 0.f;
        #pragma unroll
        for (int m = 0; m < 4; ++m) {
            float td = va[m] - cs[m];
            e = fmaf(td, td, e);
        }
        e += __shfl_xor(e, 1);
        e += __shfl_xor(e, 2);
        e += __shfl_xor(e, 4);
        e += __shfl_xor(e, 8);
        *reinterpret_cast<f32x4*>(out_vh + (size_t)grow * DKc + qo) = cs;
        if ((l & 15) == 0) {
            out_z[grow]   = (float)zsel;
            out_err[grow] = e;
            macc += (double)loss_mask[b * Lc + lrow] * (double)e;
        }
    }
    macc += __shfl_xor(macc, 16);
    macc += __shfl_xor(macc, 32);
    if (l == 0) partials[flat * 4 + w] = (float)macc;
}

// ---------------- finalize ----------------
__global__ __launch_bounds__(256) void finalize_kernel(
        const float* __restrict__ partials, int n,
        float* __restrict__ out_lcommit, float* __restrict__ out_lcode) {
    __shared__ double sh[256];
    double a = 0.0;
    for (int i = threadIdx.x; i < n; i += 256) a += (double)partials[i];
    sh[threadIdx.x] = a;
    __syncthreads();
    for (int s = 128; s; s >>= 1) {
        if (threadIdx.x < s) sh[threadIdx.x] += sh[threadIdx.x + s];
        __syncthreads();
    }
    if (threadIdx.x == 0) {
        double lc = sh[0] / (double)(Bc * Lc);
        *out_lcommit = (float)lc;
        *out_lcode   = 0.0f;
    }
}

extern "C" void kernel_launch(void* const* d_in, const int* in_sizes, int n_in,
                              void* d_out, int out_size, void* d_ws, size_t ws_size,
                              hipStream_t stream) {
    const float* vecs      = (const float*)d_in[0];
    const float* c_sum     = (const float*)d_in[1];
    const float* c_count   = (const float*)d_in[2];
    const float* loss_mask = (const float*)d_in[3];
    (void)in_sizes; (void)n_in; (void)out_size; (void)ws_size;

    char* ws = (char*)d_ws;
    float*          c        = (float*)(ws + WS_C_OFF);
    float*          c2       = (float*)(ws + WS_C2_OFF);
    unsigned short* cbh      = (unsigned short*)(ws + WS_CBH_OFF);
    unsigned short* cbl      = (unsigned short*)(ws + WS_CBL_OFF);
    float*          partials = (float*)(ws + WS_PART_OFF);

    float* out = (float*)d_out;
    float* out_vh      = out;                                   // B*H*L*DK
    float* out_z       = out + (size_t)Bc * Hc * Lc * DKc;      // B*H*L
    float* out_lcommit = out_z + (size_t)Bc * Hc * Lc;          // 1
    float* out_lcode   = out_lcommit + 1;                       // 1
    float* out_err     = out_lcode + 1;                         // B*H*L

    prep_kernel<<<(Hc * Sc * 64) / 256, 256, 0, stream>>>(c_sum, c_count, c, c2, cbh, cbl);

    vq_mfma_kernel<<<2048, 256, 0, stream>>>(vecs, c, c2, cbh, cbl, loss_mask,
                                             out_vh, out_z, out_err, partials);

    finalize_kernel<<<1, 256, 0, stream>>>(partials, NPART, out_lcommit, out_lcode);
}